// Round 15
// baseline (72.341 us; speedup 1.0000x reference)
//
#include <hip/hip_runtime.h>

#define SCALE_F 173.71779276130078f   // 400 / ln(10)
#define BLOCK 256
#define TPT 4                         // consecutive tokens per thread

typedef float v2f __attribute__((ext_vector_type(2)));

__global__ __launch_bounds__(BLOCK, 8) void strength_main_kernel(
    const float* __restrict__ x,    // [N][6]
    const float* __restrict__ W1,   // [6][32]
    const float* __restrict__ b1,   // [32]
    const float* __restrict__ wr,   // [32]
    const float* __restrict__ brp,  // scalar
    const float* __restrict__ wz,   // [32]
    const float* __restrict__ bzp,  // scalar
    const int*   __restrict__ seg,  // [N] sorted
    int N, int G, int nblocks,
    float* __restrict__ num,        // [G]
    float* __restrict__ den,        // [G]
    int*   __restrict__ ticket,     // [1], pre-zeroed
    float* __restrict__ out)        // [G]
{
    const int tid  = threadIdx.x;
    const int lane = tid & 63;

    const int t0   = blockIdx.x * (BLOCK * TPT) + tid * TPT;
    const int kmax = (t0 >= N) ? 0 : ((N - t0 < TPT) ? (N - t0) : TPT);

    // ---- load 4 consecutive tokens (6 float4 = 96B) + 4 seg ids ----
    float a[TPT * 6];
    int   sg[TPT];
    if (kmax == TPT) {
        const float4* xp = (const float4*)(x + (size_t)t0 * 6);
        #pragma unroll
        for (int i = 0; i < 6; ++i) {
            float4 v = xp[i];
            a[4 * i + 0] = v.x; a[4 * i + 1] = v.y;
            a[4 * i + 2] = v.z; a[4 * i + 3] = v.w;
        }
        int4 s0v = *(const int4*)(seg + t0);
        sg[0] = s0v.x; sg[1] = s0v.y; sg[2] = s0v.z; sg[3] = s0v.w;
    } else {
        #pragma unroll
        for (int k = 0; k < TPT; ++k) {
            if (k < kmax) {
                const float* xp = x + (size_t)(t0 + k) * 6;
                #pragma unroll
                for (int i = 0; i < 6; ++i) a[k * 6 + i] = xp[i];
                sg[k] = seg[t0 + k];
            } else {
                #pragma unroll
                for (int i = 0; i < 6; ++i) a[k * 6 + i] = 0.0f;
                sg[k] = -1;
            }
        }
    }

    // ---- token-pair packed math (v_pk_fma_f32), R9 structure ----
    v2f X[2][6];
    #pragma unroll
    for (int p = 0; p < 2; ++p)
        #pragma unroll
        for (int f = 0; f < 6; ++f)
            X[p][f] = (v2f){ a[(2*p)*6 + f], a[(2*p+1)*6 + f] };

    const float brv = *brp;   // uniform -> s_load
    const float bzv = *bzp;

    v2f R[2], Z[2];
    R[0] = (v2f){brv, brv}; R[1] = (v2f){brv, brv};
    Z[0] = (v2f){bzv, bzv}; Z[1] = (v2f){bzv, bzv};

    #pragma unroll 2
    for (int c = 0; c < 16; ++c) {
        const float2 w0 = *(const float2*)&W1[0 * 32 + 2 * c];
        const float2 w1 = *(const float2*)&W1[1 * 32 + 2 * c];
        const float2 w2 = *(const float2*)&W1[2 * 32 + 2 * c];
        const float2 w3 = *(const float2*)&W1[3 * 32 + 2 * c];
        const float2 w4 = *(const float2*)&W1[4 * 32 + 2 * c];
        const float2 w5 = *(const float2*)&W1[5 * 32 + 2 * c];
        const float2 bb = *(const float2*)&b1[2 * c];
        const float2 rr = *(const float2*)&wr[2 * c];
        const float2 zz = *(const float2*)&wz[2 * c];

        #pragma unroll
        for (int j = 0; j < 2; ++j) {   // the two columns of this pair
            const float wj0 = j ? w0.y : w0.x;
            const float wj1 = j ? w1.y : w1.x;
            const float wj2 = j ? w2.y : w2.x;
            const float wj3 = j ? w3.y : w3.x;
            const float wj4 = j ? w4.y : w4.x;
            const float wj5 = j ? w5.y : w5.x;
            const float bbj = j ? bb.y : bb.x;
            const float rrj = j ? rr.y : rr.x;
            const float zzj = j ? zz.y : zz.x;
            const v2f vw0 = (v2f){wj0, wj0}, vw1 = (v2f){wj1, wj1};
            const v2f vw2 = (v2f){wj2, wj2}, vw3 = (v2f){wj3, wj3};
            const v2f vw4 = (v2f){wj4, wj4}, vw5 = (v2f){wj5, wj5};
            const v2f vbb = (v2f){bbj, bbj};
            const v2f vrr = (v2f){rrj, rrj}, vzz = (v2f){zzj, zzj};
            #pragma unroll
            for (int p = 0; p < 2; ++p) {
                v2f h = X[p][0]*vw0 + (X[p][1]*vw1 + (X[p][2]*vw2 +
                        (X[p][3]*vw3 + (X[p][4]*vw4 + (X[p][5]*vw5 + vbb)))));
                h = __builtin_elementwise_max(h, (v2f){0.f, 0.f});   // v_pk_max_f32
                R[p] = h * vrr + R[p];
                Z[p] = h * vzz + Z[p];
            }
        }
    }

    float rv[TPT] = { R[0].x, R[0].y, R[1].x, R[1].y };
    float zv[TPT] = { Z[0].x, Z[0].y, Z[1].x, Z[1].y };

    // ---- per-thread run accumulation; interior boundary flushes to global ----
    int   key = (kmax > 0) ? sg[0] : -1;
    float E = 0.0f, ER = 0.0f;
    #pragma unroll
    for (int k = 0; k < TPT; ++k) {
        if (k < kmax) {
            float e = __expf(zv[k]);       // no max-shift: ratio invariant
            if (sg[k] != key) {            // rare (~1.5% of threads)
                atomicAdd(&den[key], E);
                atomicAdd(&num[key], ER);
                key = sg[k]; E = 0.0f; ER = 0.0f;
            }
            E += e; ER = fmaf(e, rv[k], ER);
        }
    }

    // ---- one segmented inclusive scan per wave over lane tails ----
    #pragma unroll
    for (int d = 1; d < 64; d <<= 1) {
        int   k2 = __shfl_up(key, d);
        float E2 = __shfl_up(E,   d);
        float R2 = __shfl_up(ER,  d);
        if (lane >= d && k2 == key) { E += E2; ER += R2; }
    }
    int knext = __shfl_down(key, 1);
    bool last = (lane == 63) || (knext != key);
    if (last && key >= 0) {
        atomicAdd(&den[key], E);
        atomicAdd(&num[key], ER);
    }

    // ---- fused finalize: fence-free release via vmcnt drain + ticket ----
    // Device-scope atomicAdds complete at the coherent point once vmcnt
    // retires; no cache writeback/invalidate needed (R6's fence poison).
    __shared__ int isLastS;
    asm volatile("s_waitcnt vmcnt(0)" ::: "memory");
    __syncthreads();
    if (tid == 0) {
        int t = __hip_atomic_fetch_add(ticket, 1, __ATOMIC_ACQ_REL,
                                       __HIP_MEMORY_SCOPE_AGENT);
        isLastS = (t == nblocks - 1) ? 1 : 0;
    }
    __syncthreads();
    if (isLastS) {
        for (int g = tid; g < G; g += BLOCK) {
            float d  = __hip_atomic_load(&den[g], __ATOMIC_RELAXED,
                                         __HIP_MEMORY_SCOPE_AGENT);
            float nm = __hip_atomic_load(&num[g], __ATOMIC_RELAXED,
                                         __HIP_MEMORY_SCOPE_AGENT);
            out[g] = (d > 0.0f) ? (SCALE_F * nm / d) : 0.0f;
        }
    }
}

extern "C" void kernel_launch(void* const* d_in, const int* in_sizes, int n_in,
                              void* d_out, int out_size, void* d_ws, size_t ws_size,
                              hipStream_t stream) {
    const float* x   = (const float*)d_in[0];
    const float* W1  = (const float*)d_in[1];
    const float* b1  = (const float*)d_in[2];
    const float* wr  = (const float*)d_in[3];
    const float* br  = (const float*)d_in[4];
    const float* wz  = (const float*)d_in[5];
    const float* bz  = (const float*)d_in[6];
    const int*   seg = (const int*)d_in[7];

    int N = in_sizes[7];     // 2097152
    int G = out_size;        // 8192

    float* num    = (float*)d_ws;
    float* den    = num + G;
    int*   ticket = (int*)(den + G);
    float* out    = (float*)d_out;

    // one memset node zeroes num, den, and ticket (float 0.0f == all-zero)
    hipMemsetAsync(num, 0, (size_t)(2 * G + 1) * sizeof(float), stream);

    long tokens_per_block = (long)BLOCK * TPT;   // 1024
    int  nblocks = (int)(((long)N + tokens_per_block - 1) / tokens_per_block);
    strength_main_kernel<<<nblocks, BLOCK, 0, stream>>>(
        x, W1, b1, wr, br, wz, bz, seg, N, G, nblocks, num, den, ticket, out);
}

// Round 16
// 29.064 us; speedup vs baseline: 2.4890x; 2.4890x over previous
//
#include <hip/hip_runtime.h>

#define SCALE_F 173.71779276130078f   // 400 / ln(10)
#define BLOCK 256
#define TPT 4                         // consecutive tokens per thread

typedef float v2f __attribute__((ext_vector_type(2)));

__global__ void zero_ws_kernel(float* __restrict__ ws, int n) {
    int i = blockIdx.x * 256 + threadIdx.x;
    if (i < n) ws[i] = 0.0f;
}

__global__ __launch_bounds__(BLOCK, 8) void strength_main_kernel(
    const float* __restrict__ x,    // [N][6]
    const float* __restrict__ W1,   // [6][32]
    const float* __restrict__ b1,   // [32]
    const float* __restrict__ wr,   // [32]
    const float* __restrict__ brp,  // scalar
    const float* __restrict__ wz,   // [32]
    const float* __restrict__ bzp,  // scalar
    const int*   __restrict__ seg,  // [N] sorted
    int N,
    float* __restrict__ num,        // [G]
    float* __restrict__ den)        // [G]
{
    const int tid  = threadIdx.x;
    const int lane = tid & 63;

    const int t0   = blockIdx.x * (BLOCK * TPT) + tid * TPT;
    const int kmax = (t0 >= N) ? 0 : ((N - t0 < TPT) ? (N - t0) : TPT);

    // ---- load 4 consecutive tokens (6 float4 = 96B) + 4 seg ids ----
    float a[TPT * 6];
    int   sg[TPT];
    if (kmax == TPT) {
        const float4* xp = (const float4*)(x + (size_t)t0 * 6);
        #pragma unroll
        for (int i = 0; i < 6; ++i) {
            float4 v = xp[i];
            a[4 * i + 0] = v.x; a[4 * i + 1] = v.y;
            a[4 * i + 2] = v.z; a[4 * i + 3] = v.w;
        }
        int4 s0v = *(const int4*)(seg + t0);
        sg[0] = s0v.x; sg[1] = s0v.y; sg[2] = s0v.z; sg[3] = s0v.w;
    } else {
        #pragma unroll
        for (int k = 0; k < TPT; ++k) {
            if (k < kmax) {
                const float* xp = x + (size_t)(t0 + k) * 6;
                #pragma unroll
                for (int i = 0; i < 6; ++i) a[k * 6 + i] = xp[i];
                sg[k] = seg[t0 + k];
            } else {
                #pragma unroll
                for (int i = 0; i < 6; ++i) a[k * 6 + i] = 0.0f;
                sg[k] = -1;
            }
        }
    }

    // ---- token-pair packed layout: X[p][f] = {tok(2p).f, tok(2p+1).f} ----
    v2f X[2][6];
    #pragma unroll
    for (int p = 0; p < 2; ++p)
        #pragma unroll
        for (int f = 0; f < 6; ++f)
            X[p][f] = (v2f){ a[(2*p)*6 + f], a[(2*p+1)*6 + f] };

    const float brv = *brp;   // uniform -> s_load
    const float bzv = *bzp;

    v2f R[2], Z[2];
    R[0] = (v2f){brv, brv}; R[1] = (v2f){brv, brv};
    Z[0] = (v2f){bzv, bzv}; Z[1] = (v2f){bzv, bzv};

    // ---- MLP: 16 col-pairs, tokens processed 2-wide via v_pk_fma_f32.
    //      Weights are wave-uniform global derefs -> s_load (SGPRs). ----
    #pragma unroll 2
    for (int c = 0; c < 16; ++c) {
        const float2 w0 = *(const float2*)&W1[0 * 32 + 2 * c];
        const float2 w1 = *(const float2*)&W1[1 * 32 + 2 * c];
        const float2 w2 = *(const float2*)&W1[2 * 32 + 2 * c];
        const float2 w3 = *(const float2*)&W1[3 * 32 + 2 * c];
        const float2 w4 = *(const float2*)&W1[4 * 32 + 2 * c];
        const float2 w5 = *(const float2*)&W1[5 * 32 + 2 * c];
        const float2 bb = *(const float2*)&b1[2 * c];
        const float2 rr = *(const float2*)&wr[2 * c];
        const float2 zz = *(const float2*)&wz[2 * c];

        #pragma unroll
        for (int j = 0; j < 2; ++j) {   // the two columns of this pair
            const float wj0 = j ? w0.y : w0.x;
            const float wj1 = j ? w1.y : w1.x;
            const float wj2 = j ? w2.y : w2.x;
            const float wj3 = j ? w3.y : w3.x;
            const float wj4 = j ? w4.y : w4.x;
            const float wj5 = j ? w5.y : w5.x;
            const float bbj = j ? bb.y : bb.x;
            const float rrj = j ? rr.y : rr.x;
            const float zzj = j ? zz.y : zz.x;
            const v2f vw0 = (v2f){wj0, wj0}, vw1 = (v2f){wj1, wj1};
            const v2f vw2 = (v2f){wj2, wj2}, vw3 = (v2f){wj3, wj3};
            const v2f vw4 = (v2f){wj4, wj4}, vw5 = (v2f){wj5, wj5};
            const v2f vbb = (v2f){bbj, bbj};
            const v2f vrr = (v2f){rrj, rrj}, vzz = (v2f){zzj, zzj};
            #pragma unroll
            for (int p = 0; p < 2; ++p) {
                v2f h = X[p][0]*vw0 + (X[p][1]*vw1 + (X[p][2]*vw2 +
                        (X[p][3]*vw3 + (X[p][4]*vw4 + (X[p][5]*vw5 + vbb)))));
                h = __builtin_elementwise_max(h, (v2f){0.f, 0.f});   // v_pk_max_f32
                R[p] = h * vrr + R[p];
                Z[p] = h * vzz + Z[p];
            }
        }
    }

    float rv[TPT] = { R[0].x, R[0].y, R[1].x, R[1].y };
    float zv[TPT] = { Z[0].x, Z[0].y, Z[1].x, Z[1].y };

    // ---- per-thread run accumulation; interior boundary flushes to global ----
    int   key = (kmax > 0) ? sg[0] : -1;
    float E = 0.0f, ER = 0.0f;
    #pragma unroll
    for (int k = 0; k < TPT; ++k) {
        if (k < kmax) {
            float e = __expf(zv[k]);       // no max-shift: ratio invariant
            if (sg[k] != key) {            // rare (~1.5% of threads)
                atomicAdd(&den[key], E);
                atomicAdd(&num[key], ER);
                key = sg[k]; E = 0.0f; ER = 0.0f;
            }
            E += e; ER = fmaf(e, rv[k], ER);
        }
    }

    // ---- one segmented inclusive scan per wave over lane tails ----
    #pragma unroll
    for (int d = 1; d < 64; d <<= 1) {
        int   k2 = __shfl_up(key, d);
        float E2 = __shfl_up(E,   d);
        float R2 = __shfl_up(ER,  d);
        if (lane >= d && k2 == key) { E += E2; ER += R2; }
    }
    int knext = __shfl_down(key, 1);
    bool last = (lane == 63) || (knext != key);
    if (last && key >= 0) {
        atomicAdd(&den[key], E);
        atomicAdd(&num[key], ER);
    }
}

__global__ void finalize_kernel(const float* __restrict__ num,
                                const float* __restrict__ den,
                                float* __restrict__ out, int G) {
    int g = blockIdx.x * 256 + threadIdx.x;
    if (g < G) {
        float d = den[g];
        out[g] = (d > 0.0f) ? (SCALE_F * num[g] / d) : 0.0f;
    }
}

extern "C" void kernel_launch(void* const* d_in, const int* in_sizes, int n_in,
                              void* d_out, int out_size, void* d_ws, size_t ws_size,
                              hipStream_t stream) {
    const float* x   = (const float*)d_in[0];
    const float* W1  = (const float*)d_in[1];
    const float* b1  = (const float*)d_in[2];
    const float* wr  = (const float*)d_in[3];
    const float* br  = (const float*)d_in[4];
    const float* wz  = (const float*)d_in[5];
    const float* bz  = (const float*)d_in[6];
    const int*   seg = (const int*)d_in[7];

    int N = in_sizes[7];     // 2097152
    int G = out_size;        // 8192

    float* num = (float*)d_ws;
    float* den = num + G;
    float* out = (float*)d_out;

    int zn = 2 * G;
    zero_ws_kernel<<<(zn + 255) / 256, 256, 0, stream>>>(num, zn);

    long tokens_per_block = (long)BLOCK * TPT;   // 1024
    int  nblocks = (int)(((long)N + tokens_per_block - 1) / tokens_per_block);
    strength_main_kernel<<<nblocks, BLOCK, 0, stream>>>(
        x, W1, b1, wr, br, wz, bz, seg, N, num, den);

    finalize_kernel<<<(G + 255) / 256, 256, 0, stream>>>(num, den, out, G);
}

// Round 17
// 28.967 us; speedup vs baseline: 2.4973x; 1.0033x over previous
//
#include <hip/hip_runtime.h>

#define SCALE_F 173.71779276130078f   // 400 / ln(10)
#define BLOCK 256
#define TPT 4                         // consecutive tokens per thread

typedef float v2f __attribute__((ext_vector_type(2)));

__global__ __launch_bounds__(BLOCK, 8) void strength_main_kernel(
    const float* __restrict__ x,    // [N][6]
    const float* __restrict__ W1,   // [6][32]
    const float* __restrict__ b1,   // [32]
    const float* __restrict__ wr,   // [32]
    const float* __restrict__ brp,  // scalar
    const float* __restrict__ wz,   // [32]
    const float* __restrict__ bzp,  // scalar
    const int*   __restrict__ seg,  // [N] sorted
    int N,
    float* __restrict__ num,        // [G]
    float* __restrict__ den)        // [G]
{
    const int tid  = threadIdx.x;
    const int lane = tid & 63;

    const int t0   = blockIdx.x * (BLOCK * TPT) + tid * TPT;
    const int kmax = (t0 >= N) ? 0 : ((N - t0 < TPT) ? (N - t0) : TPT);

    // ---- load 4 consecutive tokens (6 float4 = 96B) + 4 seg ids ----
    float a[TPT * 6];
    int   sg[TPT];
    if (kmax == TPT) {
        const float4* xp = (const float4*)(x + (size_t)t0 * 6);
        #pragma unroll
        for (int i = 0; i < 6; ++i) {
            float4 v = xp[i];
            a[4 * i + 0] = v.x; a[4 * i + 1] = v.y;
            a[4 * i + 2] = v.z; a[4 * i + 3] = v.w;
        }
        int4 s0v = *(const int4*)(seg + t0);
        sg[0] = s0v.x; sg[1] = s0v.y; sg[2] = s0v.z; sg[3] = s0v.w;
    } else {
        #pragma unroll
        for (int k = 0; k < TPT; ++k) {
            if (k < kmax) {
                const float* xp = x + (size_t)(t0 + k) * 6;
                #pragma unroll
                for (int i = 0; i < 6; ++i) a[k * 6 + i] = xp[i];
                sg[k] = seg[t0 + k];
            } else {
                #pragma unroll
                for (int i = 0; i < 6; ++i) a[k * 6 + i] = 0.0f;
                sg[k] = -1;
            }
        }
    }

    // ---- token-pair packed layout: X[p][f] = {tok(2p).f, tok(2p+1).f} ----
    v2f X[2][6];
    #pragma unroll
    for (int p = 0; p < 2; ++p)
        #pragma unroll
        for (int f = 0; f < 6; ++f)
            X[p][f] = (v2f){ a[(2*p)*6 + f], a[(2*p+1)*6 + f] };

    const float brv = *brp;   // uniform -> s_load
    const float bzv = *bzp;

    v2f R[2], Z[2];
    R[0] = (v2f){brv, brv}; R[1] = (v2f){brv, brv};
    Z[0] = (v2f){bzv, bzv}; Z[1] = (v2f){bzv, bzv};

    // ---- MLP: 16 col-pairs, tokens processed 2-wide via v_pk_fma_f32.
    //      Weights are wave-uniform global derefs -> s_load (SGPRs). ----
    #pragma unroll 2
    for (int c = 0; c < 16; ++c) {
        const float2 w0 = *(const float2*)&W1[0 * 32 + 2 * c];
        const float2 w1 = *(const float2*)&W1[1 * 32 + 2 * c];
        const float2 w2 = *(const float2*)&W1[2 * 32 + 2 * c];
        const float2 w3 = *(const float2*)&W1[3 * 32 + 2 * c];
        const float2 w4 = *(const float2*)&W1[4 * 32 + 2 * c];
        const float2 w5 = *(const float2*)&W1[5 * 32 + 2 * c];
        const float2 bb = *(const float2*)&b1[2 * c];
        const float2 rr = *(const float2*)&wr[2 * c];
        const float2 zz = *(const float2*)&wz[2 * c];

        #pragma unroll
        for (int j = 0; j < 2; ++j) {   // the two columns of this pair
            const float wj0 = j ? w0.y : w0.x;
            const float wj1 = j ? w1.y : w1.x;
            const float wj2 = j ? w2.y : w2.x;
            const float wj3 = j ? w3.y : w3.x;
            const float wj4 = j ? w4.y : w4.x;
            const float wj5 = j ? w5.y : w5.x;
            const float bbj = j ? bb.y : bb.x;
            const float rrj = j ? rr.y : rr.x;
            const float zzj = j ? zz.y : zz.x;
            const v2f vw0 = (v2f){wj0, wj0}, vw1 = (v2f){wj1, wj1};
            const v2f vw2 = (v2f){wj2, wj2}, vw3 = (v2f){wj3, wj3};
            const v2f vw4 = (v2f){wj4, wj4}, vw5 = (v2f){wj5, wj5};
            const v2f vbb = (v2f){bbj, bbj};
            const v2f vrr = (v2f){rrj, rrj}, vzz = (v2f){zzj, zzj};
            #pragma unroll
            for (int p = 0; p < 2; ++p) {
                v2f h = X[p][0]*vw0 + (X[p][1]*vw1 + (X[p][2]*vw2 +
                        (X[p][3]*vw3 + (X[p][4]*vw4 + (X[p][5]*vw5 + vbb)))));
                h = __builtin_elementwise_max(h, (v2f){0.f, 0.f});   // v_pk_max_f32
                R[p] = h * vrr + R[p];
                Z[p] = h * vzz + Z[p];
            }
        }
    }

    float rv[TPT] = { R[0].x, R[0].y, R[1].x, R[1].y };
    float zv[TPT] = { Z[0].x, Z[0].y, Z[1].x, Z[1].y };

    // ---- per-thread run accumulation; interior boundary flushes to global ----
    int   key = (kmax > 0) ? sg[0] : -1;
    float E = 0.0f, ER = 0.0f;
    #pragma unroll
    for (int k = 0; k < TPT; ++k) {
        if (k < kmax) {
            float e = __expf(zv[k]);       // no max-shift: ratio invariant
            if (sg[k] != key) {            // rare (~1.5% of threads)
                atomicAdd(&den[key], E);
                atomicAdd(&num[key], ER);
                key = sg[k]; E = 0.0f; ER = 0.0f;
            }
            E += e; ER = fmaf(e, rv[k], ER);
        }
    }

    // ---- one segmented inclusive scan per wave over lane tails ----
    #pragma unroll
    for (int d = 1; d < 64; d <<= 1) {
        int   k2 = __shfl_up(key, d);
        float E2 = __shfl_up(E,   d);
        float R2 = __shfl_up(ER,  d);
        if (lane >= d && k2 == key) { E += E2; ER += R2; }
    }
    int knext = __shfl_down(key, 1);
    bool last = (lane == 63) || (knext != key);
    if (last && key >= 0) {
        atomicAdd(&den[key], E);
        atomicAdd(&num[key], ER);
    }
}

__global__ void finalize_kernel(const float* __restrict__ num,
                                const float* __restrict__ den,
                                float* __restrict__ out, int G) {
    int g = blockIdx.x * 256 + threadIdx.x;
    if (g < G) {
        float d = den[g];
        out[g] = (d > 0.0f) ? (SCALE_F * num[g] / d) : 0.0f;
    }
}

extern "C" void kernel_launch(void* const* d_in, const int* in_sizes, int n_in,
                              void* d_out, int out_size, void* d_ws, size_t ws_size,
                              hipStream_t stream) {
    const float* x   = (const float*)d_in[0];
    const float* W1  = (const float*)d_in[1];
    const float* b1  = (const float*)d_in[2];
    const float* wr  = (const float*)d_in[3];
    const float* br  = (const float*)d_in[4];
    const float* wz  = (const float*)d_in[5];
    const float* bz  = (const float*)d_in[6];
    const int*   seg = (const int*)d_in[7];

    int N = in_sizes[7];     // 2097152
    int G = out_size;        // 8192

    float* num = (float*)d_ws;
    float* den = num + G;
    float* out = (float*)d_out;

    // memset node instead of a zero-kernel dispatch (float 0.0f == all-zero)
    hipMemsetAsync(num, 0, (size_t)(2 * G) * sizeof(float), stream);

    long tokens_per_block = (long)BLOCK * TPT;   // 1024
    int  nblocks = (int)(((long)N + tokens_per_block - 1) / tokens_per_block);
    strength_main_kernel<<<nblocks, BLOCK, 0, stream>>>(
        x, W1, b1, wr, br, wz, bz, seg, N, num, den);

    finalize_kernel<<<(G + 255) / 256, 256, 0, stream>>>(num, den, out, G);
}